// Round 2
// baseline (332.167 us; speedup 1.0000x reference)
//
#include <hip/hip_runtime.h>

// CostVolume2D: N=8, C=128, H=96, W=224, D=4 -> 81 channels.
// out[n, dy*9+dx, h, w] = mean_c f1[n,c,h,w] * f2[n,c,h+dy-4,w+dx-4] (0 if OOB)
//
// Round 6: barrier-free rewrite. Round-5 post-mortem: lgkm-only barrier +
// 2-deep prefetch left VALUBusy at 28% and dur at 133us -- the stall is the
// per-channel 3-wave barrier convoy itself (plus 30% occupancy), not the
// vmcnt drain. This version removes LDS and ALL synchronization:
//  - each 64-thread block = ONE wave handling one (tile, dy) pair; grid
//    336 tiles x 9 dy = 3024 blocks -> 12 free-running waves/CU.
//  - f2 window read directly via hardware-bounds-checked buffer_load:
//    SRD num_records = one channel slab (HW*4 bytes) makes vertical OOB
//    return 0 in HW; horizontal OOB granules get a poisoned voffset
//    (0x70000000 > num_records) -> also return 0. Zero masking code.
//  - f2 inter-thread overlap (16-float windows, stride 8) served by L1;
//    the 9 dy-waves of a tile share an XCD (swizzle) so L2 serves re-reads.
//  - 1-channel-ahead ping-pong register prefetch (A/B sets), no waits
//    except compiler-counted vmcnt on consumption.
// Per thread: 8 w-px x 1 row x 9 dx = 72 fp32 accumulators, 72 FMA/channel.

constexpr int Cn = 128;
constexpr int Hh = 96;
constexpr int Ww = 224;
constexpr int HW = Hh * Ww;       // 21504
constexpr int HWB = HW * 4;       // channel slab bytes = 86016
constexpr int TILE_H = 16;
constexpr int TILE_W = 32;

typedef int   int32x4 __attribute__((ext_vector_type(4)));
typedef float fltx4   __attribute__((ext_vector_type(4)));

// Legacy raw buffer load (CK-style binding): srsrc, voffset(B), soffset(B), aux.
// OOB (voffset+soffset+16 > num_records) returns 0 and never faults.
__device__ fltx4 llvm_amdgcn_raw_buffer_load_fp32x4(int32x4 srsrc, int voffset,
                                                    int soffset, int aux)
    __asm("llvm.amdgcn.raw.buffer.load.v4f32");

__device__ __forceinline__ int32x4 make_rsrc(unsigned long long base_bytes) {
    int32x4 r;
    r.x = (int)(base_bytes & 0xffffffffull);
    r.y = (int)(base_bytes >> 32);
    r.z = HWB;               // num_records: exactly one channel slab
    r.w = 0x00020000;        // raw dword buffer
    return r;
}

__global__ __launch_bounds__(64, 3)
void costvol_kernel(const float* __restrict__ f1g, const float* __restrict__ f2g,
                    float* __restrict__ outg) {
    const int b    = blockIdx.x;
    const int xcd  = b & 7;            // consecutive block IDs round-robin XCDs
    const int j    = b >> 3;           // 0..377
    const int dy   = j % 9;
    const int tp   = j / 9;            // 0..41
    const int tile = tp * 8 + xcd;     // a tile's 9 dy-waves -> same XCD
    const int wt   = tile % 7;
    const int ht   = (tile / 7) % 6;
    const int n    = tile / 42;

    const int h0 = ht * TILE_H;
    const int w0 = wt * TILE_W;

    const int lane = threadIdx.x;      // one wave per block
    const int gx   = lane & 3;         // 8 w px: w = w0 + 8*gx + (0..7)
    const int gy   = lane >> 2;        // h row: h = h0 + gy
    const int hA   = h0 + gy;
    const int wA   = w0 + 8 * gx;

    // f2 row for this wave's dy; window cols [wA-4, wA+12) = 4 aligned granules
    const int  y     = hA + dy - 4;
    const bool rowOk = (y >= 0) && (y < Hh);
    constexpr int POISON = 0x70000000;          // OOB for any channel slab
    const int vbase = (y * Ww + wA - 4) * 4;    // byte offset of granule 0
    const int vo0 = (rowOk && wA != 0)   ? vbase      : POISON;
    const int vo1 = rowOk                ? vbase + 16 : POISON;
    const int vo2 = rowOk                ? vbase + 32 : POISON;
    const int vo3 = (rowOk && wA != 216) ? vbase + 48 : POISON;
    const int f1vo = (hA * Ww + wA) * 4;        // always in-bounds

    const unsigned long long f2a =
        (unsigned long long)(f2g + (size_t)n * Cn * HW);
    const unsigned long long f1a =
        (unsigned long long)(f1g + (size_t)n * Cn * HW);

    float4 acc[2][9];
#pragma unroll
    for (int p = 0; p < 2; ++p)
#pragma unroll
        for (int dx = 0; dx < 9; ++dx)
            acc[p][dx] = make_float4(0.f, 0.f, 0.f, 0.f);

    // ---- prologue: channel 0 -> A set ----
    fltx4 qA0, qA1, qA2, qA3, a0A, a1A;
    fltx4 qB0, qB1, qB2, qB3, a0B, a1B;
    {
        const int32x4 r2 = make_rsrc(f2a);
        const int32x4 r1 = make_rsrc(f1a);
        qA0 = llvm_amdgcn_raw_buffer_load_fp32x4(r2, vo0, 0, 0);
        qA1 = llvm_amdgcn_raw_buffer_load_fp32x4(r2, vo1, 0, 0);
        qA2 = llvm_amdgcn_raw_buffer_load_fp32x4(r2, vo2, 0, 0);
        qA3 = llvm_amdgcn_raw_buffer_load_fp32x4(r2, vo3, 0, 0);
        a0A = llvm_amdgcn_raw_buffer_load_fp32x4(r1, f1vo, 0, 0);
        a1A = llvm_amdgcn_raw_buffer_load_fp32x4(r1, f1vo, 16, 0);
    }

#pragma unroll 1
    for (int cc = 0; cc < Cn; cc += 2) {
        // ---- prefetch channel cc+1 -> B (cc+1 <= 127 always) ----
        {
            const unsigned long long o = (unsigned long long)(cc + 1) * HWB;
            const int32x4 r2 = make_rsrc(f2a + o);
            const int32x4 r1 = make_rsrc(f1a + o);
            qB0 = llvm_amdgcn_raw_buffer_load_fp32x4(r2, vo0, 0, 0);
            qB1 = llvm_amdgcn_raw_buffer_load_fp32x4(r2, vo1, 0, 0);
            qB2 = llvm_amdgcn_raw_buffer_load_fp32x4(r2, vo2, 0, 0);
            qB3 = llvm_amdgcn_raw_buffer_load_fp32x4(r2, vo3, 0, 0);
            a0B = llvm_amdgcn_raw_buffer_load_fp32x4(r1, f1vo, 0, 0);
            a1B = llvm_amdgcn_raw_buffer_load_fp32x4(r1, f1vo, 16, 0);
        }
        // ---- compute channel cc with A ----
        {
            const fltx4 a0 = a0A, a1 = a1A;
            const float wv[16] = {qA0.x, qA0.y, qA0.z, qA0.w,
                                  qA1.x, qA1.y, qA1.z, qA1.w,
                                  qA2.x, qA2.y, qA2.z, qA2.w,
                                  qA3.x, qA3.y, qA3.z, qA3.w};
#pragma unroll
            for (int dx = 0; dx < 9; ++dx) {
                acc[0][dx].x += a0.x * wv[dx + 0];
                acc[0][dx].y += a0.y * wv[dx + 1];
                acc[0][dx].z += a0.z * wv[dx + 2];
                acc[0][dx].w += a0.w * wv[dx + 3];
                acc[1][dx].x += a1.x * wv[dx + 4];
                acc[1][dx].y += a1.y * wv[dx + 5];
                acc[1][dx].z += a1.z * wv[dx + 6];
                acc[1][dx].w += a1.w * wv[dx + 7];
            }
        }
        // ---- prefetch channel cc+2 -> A (clamped; harmless reload at end) ----
        {
            const int c2 = (cc + 2 < Cn) ? (cc + 2) : cc;
            const unsigned long long o = (unsigned long long)c2 * HWB;
            const int32x4 r2 = make_rsrc(f2a + o);
            const int32x4 r1 = make_rsrc(f1a + o);
            qA0 = llvm_amdgcn_raw_buffer_load_fp32x4(r2, vo0, 0, 0);
            qA1 = llvm_amdgcn_raw_buffer_load_fp32x4(r2, vo1, 0, 0);
            qA2 = llvm_amdgcn_raw_buffer_load_fp32x4(r2, vo2, 0, 0);
            qA3 = llvm_amdgcn_raw_buffer_load_fp32x4(r2, vo3, 0, 0);
            a0A = llvm_amdgcn_raw_buffer_load_fp32x4(r1, f1vo, 0, 0);
            a1A = llvm_amdgcn_raw_buffer_load_fp32x4(r1, f1vo, 16, 0);
        }
        // ---- compute channel cc+1 with B ----
        {
            const fltx4 a0 = a0B, a1 = a1B;
            const float wv[16] = {qB0.x, qB0.y, qB0.z, qB0.w,
                                  qB1.x, qB1.y, qB1.z, qB1.w,
                                  qB2.x, qB2.y, qB2.z, qB2.w,
                                  qB3.x, qB3.y, qB3.z, qB3.w};
#pragma unroll
            for (int dx = 0; dx < 9; ++dx) {
                acc[0][dx].x += a0.x * wv[dx + 0];
                acc[0][dx].y += a0.y * wv[dx + 1];
                acc[0][dx].z += a0.z * wv[dx + 2];
                acc[0][dx].w += a0.w * wv[dx + 3];
                acc[1][dx].x += a1.x * wv[dx + 4];
                acc[1][dx].y += a1.y * wv[dx + 5];
                acc[1][dx].z += a1.z * wv[dx + 6];
                acc[1][dx].w += a1.w * wv[dx + 7];
            }
        }
    }

    // ---- writeout: 2 x 9 float4 per thread, coalesced 16B stores ----
    const float sc = 1.0f / 128.0f;
    float* ob = outg + (size_t)n * 81 * HW + (size_t)hA * Ww + wA;
#pragma unroll
    for (int dx = 0; dx < 9; ++dx) {
        const int k = dy * 9 + dx;
#pragma unroll
        for (int p = 0; p < 2; ++p) {
            float4 v = acc[p][dx];
            v.x *= sc; v.y *= sc; v.z *= sc; v.w *= sc;
            *(float4*)(ob + (size_t)k * HW + 4 * p) = v;
        }
    }
}

extern "C" void kernel_launch(void* const* d_in, const int* in_sizes, int n_in,
                              void* d_out, int out_size, void* d_ws, size_t ws_size,
                              hipStream_t stream) {
    const float* f1 = (const float*)d_in[0];
    const float* f2 = (const float*)d_in[1];
    float* out = (float*)d_out;
    // grid: 336 tiles x 9 dy, swizzled so a tile's 9 waves share an XCD
    costvol_kernel<<<dim3(3024), dim3(64), 0, stream>>>(f1, f2, out);
}